// Round 10
// baseline (3101.582 us; speedup 1.0000x reference)
//
#include <hip/hip_runtime.h>
#include <cstdint>
#include <cstddef>

#define IN_F 512
#define OUT_F 1024
#define BATCH 8192
#define W_K 1535   // IN_F + OUT_F - 1
#define SROW 132   // padded t-dimension (16B-aligned rows, conflict-free quads)

// ---------------------------------------------------------------------------
__global__ __launch_bounds__(256) void k_fill(float* __restrict__ out, float val) {
  const size_t i = ((size_t)blockIdx.x * 256 + threadIdx.x) * 4;
  float4 v; v.x = v.y = v.z = v.w = val;
  *(float4*)(out + i) = v;
}

// ---------------------------------------------------------------------------
// K1: xw = x @ Wx.T + bias mimicking numpy/OpenBLAS sgemm fp32 rounding:
// one fp32 accumulator per C element, FMA, k strictly ascending, single RNE
// bias add. UNCHANGED from the passing R9 kernel (bit-exactness preserved).
// ---------------------------------------------------------------------------
__global__ __launch_bounds__(256) void k_gemm32(const float* __restrict__ x,
                                                const float* __restrict__ w,
                                                const float* __restrict__ bias,
                                                float* __restrict__ xw) {
  __shared__ float xs[64][33];
  __shared__ float wsh[64][33];
  const int t = threadIdx.x;
  const int bsub = t >> 4;    // 0..15 -> 4 b-rows
  const int esub = t & 15;    // 0..15 -> 4 e-cols
  const int bm = blockIdx.x;  // 128 tiles of 64 rows
  const int bn = blockIdx.y;  // 16 tiles of 64 cols
  const int srow = t >> 2;          // staging row 0..63
  const int scol = (t & 3) * 8;     // staging k-offset
  const float* xbase = x + (size_t)(bm * 64 + srow) * IN_F + scol;
  const float* wbase = w + (size_t)(bn * 64 + srow) * W_K + scol;

  float acc[4][4];
#pragma unroll
  for (int a = 0; a < 4; ++a)
#pragma unroll
    for (int b = 0; b < 4; ++b) acc[a][b] = 0.0f;

  for (int k0 = 0; k0 < IN_F; k0 += 32) {
    float xv[8], wv[8];
#pragma unroll
    for (int c = 0; c < 8; ++c) { xv[c] = xbase[k0 + c]; wv[c] = wbase[k0 + c]; }
    __syncthreads();
#pragma unroll
    for (int c = 0; c < 8; ++c) { xs[srow][scol + c] = xv[c]; wsh[srow][scol + c] = wv[c]; }
    __syncthreads();
#pragma unroll
    for (int k = 0; k < 32; ++k) {   // ascending k: exact BLAS accumulation order
      const float a0 = xs[bsub * 4 + 0][k], a1 = xs[bsub * 4 + 1][k];
      const float a2 = xs[bsub * 4 + 2][k], a3 = xs[bsub * 4 + 3][k];
      const float b0 = wsh[esub * 4 + 0][k], b1 = wsh[esub * 4 + 1][k];
      const float b2 = wsh[esub * 4 + 2][k], b3 = wsh[esub * 4 + 3][k];
      acc[0][0] = fmaf(a0, b0, acc[0][0]); acc[0][1] = fmaf(a0, b1, acc[0][1]);
      acc[0][2] = fmaf(a0, b2, acc[0][2]); acc[0][3] = fmaf(a0, b3, acc[0][3]);
      acc[1][0] = fmaf(a1, b0, acc[1][0]); acc[1][1] = fmaf(a1, b1, acc[1][1]);
      acc[1][2] = fmaf(a1, b2, acc[1][2]); acc[1][3] = fmaf(a1, b3, acc[1][3]);
      acc[2][0] = fmaf(a2, b0, acc[2][0]); acc[2][1] = fmaf(a2, b1, acc[2][1]);
      acc[2][2] = fmaf(a2, b2, acc[2][2]); acc[2][3] = fmaf(a2, b3, acc[2][3]);
      acc[3][0] = fmaf(a3, b0, acc[3][0]); acc[3][1] = fmaf(a3, b1, acc[3][1]);
      acc[3][2] = fmaf(a3, b2, acc[3][2]); acc[3][3] = fmaf(a3, b3, acc[3][3]);
    }
  }

#pragma unroll
  for (int ie = 0; ie < 4; ++ie) {
    const int e = bn * 64 + esub * 4 + ie;
    const float bv = bias[e];
#pragma unroll
    for (int ib = 0; ib < 4; ++ib) {
      const int b = bm * 64 + bsub * 4 + ib;
      xw[(size_t)b * OUT_F + e] = acc[ib][ie] + bv;   // single RNE add, like np
    }
  }
}

// ---------------------------------------------------------------------------
// K2: the scan (OpenBLAS sgemv_t fp32 mimicry — bit-identical arithmetic to
// the R9 passing kernel; only the SCHEDULE changed):
//   - Wo row double-buffered in LDS; row i+1 prefetched into registers at the
//     top of step i, committed to the alternate buffer at step end (hides the
//     ~200cyc L2 latency that serialized R9's staging).
//   - dot loop is STATIC full-length (t = 0..127): terms beyond the live
//     range read zero-initialized LDS -> exact +0.0 adds (bit-neutral, same
//     justification as R9's skipping) -> compiler batches all ds_read_b128.
//   - xw[i], u[i] loaded at step top on all lanes (uniform per group),
//     consumed ~800cyc later after the dot.
// Layout unchanged: 8 rows/wave, lane m owns partial m (j ≡ m mod 8,
// ascending, FMA), AVX tree ((P0+P4)+(P2+P6))+((P1+P5)+(P3+P7)), scalar tail
// j=1016..1022, logit = xw_i + dot, sigma in double rounded to fp32.
// 1024 blocks x 64 threads (1 wave -> no barriers; launch_bounds(64,1) frees
// the full VGPR budget for load batching).
// ---------------------------------------------------------------------------
__global__ __launch_bounds__(64, 1) void k_scan32(const float* __restrict__ w,
                                                  const float* __restrict__ u,
                                                  const float* __restrict__ xw,
                                                  float* __restrict__ out_s,
                                                  float* __restrict__ out_l) {
  __shared__ float smp[8][8][SROW];     // 33.8 KiB  samples, permuted
  __shared__ float wop[2][8][SROW];     //  8.4 KiB  Wo row, double-buffered
  __shared__ float tail_smp[8][8];      //  samples j in [1016,1024)
  const int lane = threadIdx.x;
  const int g = lane >> 3;   // row group 0..7
  const int m = lane & 7;    // partial index

  // zero-init LDS (harness poisons; zeros are bit-exact filler terms)
  for (int idx = lane; idx < 8 * 8 * SROW; idx += 64) (&smp[0][0][0])[idx] = 0.0f;
  for (int idx = lane; idx < 2 * 8 * SROW; idx += 64) (&wop[0][0][0])[idx] = 0.0f;
  if (lane < 8) { for (int jj = 0; jj < 8; ++jj) tail_smp[lane][jj] = 0.0f; }

  const int r = blockIdx.x * 8 + g;
  const float* xwr = xw + (size_t)r * OUT_F;
  const float* ur = u + (size_t)r * OUT_F;
  float* osr = out_s + (size_t)r * OUT_F;
  float* olr = out_l + (size_t)r * OUT_F;

  // stage row 0 into wop[0]
  {
    const float* w0 = w + (size_t)0 * W_K + IN_F;
#pragma unroll
    for (int c = 0; c < 16; ++c) {
      const int jj = lane + 64 * c;
      if (jj < OUT_F - 1) wop[0][jj & 7][jj >> 3] = w0[jj];
    }
  }

  for (int i = 0; i < OUT_F; ++i) {
    const int cur = i & 1, nxt = cur ^ 1;

    // ---- prefetch row i+1 into registers (independent loads, no waits) ----
    float pre[16];
    const bool havenext = (i + 1 < OUT_F);
    if (havenext) {
      const float* wn = w + (size_t)(i + 1) * W_K + IN_F;
#pragma unroll
      for (int c = 0; c < 16; ++c) {
        const int jj = lane + 64 * c;
        pre[c] = wn[(jj < OUT_F - 1) ? jj : 0];  // clamped (clamp value unused)
      }
    }
    // ---- prefetch this step's xw/u (uniform per group; consumed post-dot) --
    const float xwc = xwr[i];
    const float uc = ur[i];

    // ---- vector-region partial P_m: static full-length, ascending t, FMA ---
    float P = 0.0f;
    const float* sp = &smp[g][m][0];
    const float* wp = &wop[cur][m][0];
#pragma unroll
    for (int q = 0; q < 32; ++q) {
      const float4 s4 = *(const float4*)(sp + 4 * q);
      const float4 w4 = *(const float4*)(wp + 4 * q);
      P = fmaf(s4.x, w4.x, P);
      P = fmaf(s4.y, w4.y, P);
      P = fmaf(s4.z, w4.z, P);
      P = fmaf(s4.w, w4.w, P);
    }

    // ---- AVX horizontal tree: ((P0+P4)+(P2+P6)) + ((P1+P5)+(P3+P7)) --------
    float t1 = P + __shfl_xor(P, 4);
    float t2 = t1 + __shfl_xor(t1, 2);
    float T = t2 + __shfl_xor(t2, 1);

    // ---- lane m==0: scalar tail, logit, sigma, decision, writes ------------
    if (m == 0) {
#pragma unroll
      for (int jj = 0; jj < 7; ++jj)
        T = fmaf(tail_smp[g][jj], wop[cur][jj][127], T);
      const float L = xwc + T;                          // np: xw_i + dot
      const double sd = 1.0 / (1.0 + exp(-(double)L));  // sigma (double, RNE)
      const float sig = (float)sd;
      const float s = (uc < sig) ? 1.0f : 0.0f;
      if (i < 1016) smp[g][i & 7][i >> 3] = s;
      else tail_smp[g][i - 1016] = s;
      osr[i] = s;
      olr[i] = L;
    }

    // ---- commit prefetched row into the alternate buffer -------------------
    if (havenext) {
#pragma unroll
      for (int c = 0; c < 16; ++c) {
        const int jj = lane + 64 * c;
        if (jj < OUT_F - 1) wop[nxt][jj & 7][jj >> 3] = pre[c];
      }
    }
  }
}

// ---------------------------------------------------------------------------
extern "C" void kernel_launch(void* const* d_in, const int* in_sizes, int n_in,
                              void* d_out, int out_size, void* d_ws, size_t ws_size,
                              hipStream_t stream) {
  float* out_s = (float*)d_out;                      // samples (B x OUT_F) fp32
  float* out_l = out_s + (size_t)BATCH * OUT_F;      // logits  (B x OUT_F) fp32
  const int nfill = (BATCH * OUT_F) / (256 * 4);

  const bool shapes_ok =
      n_in == 4 &&
      in_sizes[0] == BATCH * IN_F && in_sizes[1] == OUT_F * W_K &&
      in_sizes[2] == OUT_F && in_sizes[3] == BATCH * OUT_F &&
      out_size == 2 * BATCH * OUT_F;
  if (!shapes_ok) {
    k_fill<<<nfill, 256, 0, stream>>>(out_s, 11.0f);
    return;
  }

  const size_t xw_bytes = (size_t)BATCH * OUT_F * sizeof(float);  // 32 MiB
  if (ws_size < xw_bytes) {
    k_fill<<<nfill, 256, 0, stream>>>(out_s, 7.0f);
    return;
  }

  const float* x = (const float*)d_in[0];     // fp32 (8192 x 512)
  const float* w = (const float*)d_in[1];     // fp32 (1024 x 1535)
  const float* bias = (const float*)d_in[2];  // fp32 (1024)
  const float* u = (const float*)d_in[3];     // fp32 (8192 x 1024)
  float* xw = (float*)d_ws;                   // 32 MiB

  k_gemm32<<<dim3(BATCH / 64, OUT_F / 64), 256, 0, stream>>>(x, w, bias, xw);
  k_scan32<<<BATCH / 8, 64, 0, stream>>>(w, u, xw, out_s, out_l);
}

// Round 11
// 2480.235 us; speedup vs baseline: 1.2505x; 1.2505x over previous
//
#include <hip/hip_runtime.h>
#include <cstdint>
#include <cstddef>

#define IN_F 512
#define OUT_F 1024
#define BATCH 8192
#define W_K 1535   // IN_F + OUT_F - 1
#define SROW 132   // stride ≡ 4 (mod 32) banks -> b128 wave reads perfectly spread

// ---------------------------------------------------------------------------
__global__ __launch_bounds__(256) void k_fill(float* __restrict__ out, float val) {
  const size_t i = ((size_t)blockIdx.x * 256 + threadIdx.x) * 4;
  float4 v; v.x = v.y = v.z = v.w = val;
  *(float4*)(out + i) = v;
}

// ---------------------------------------------------------------------------
// K1: xw = x @ Wx.T + bias mimicking numpy/OpenBLAS sgemm fp32 rounding:
// one fp32 accumulator per C element, FMA, k strictly ascending, single RNE
// bias add. UNCHANGED from the passing R9/R10 kernel (bit-exact).
// ---------------------------------------------------------------------------
__global__ __launch_bounds__(256) void k_gemm32(const float* __restrict__ x,
                                                const float* __restrict__ w,
                                                const float* __restrict__ bias,
                                                float* __restrict__ xw) {
  __shared__ float xs[64][33];
  __shared__ float wsh[64][33];
  const int t = threadIdx.x;
  const int bsub = t >> 4;
  const int esub = t & 15;
  const int bm = blockIdx.x;
  const int bn = blockIdx.y;
  const int srow = t >> 2;
  const int scol = (t & 3) * 8;
  const float* xbase = x + (size_t)(bm * 64 + srow) * IN_F + scol;
  const float* wbase = w + (size_t)(bn * 64 + srow) * W_K + scol;

  float acc[4][4];
#pragma unroll
  for (int a = 0; a < 4; ++a)
#pragma unroll
    for (int b = 0; b < 4; ++b) acc[a][b] = 0.0f;

  for (int k0 = 0; k0 < IN_F; k0 += 32) {
    float xv[8], wv[8];
#pragma unroll
    for (int c = 0; c < 8; ++c) { xv[c] = xbase[k0 + c]; wv[c] = wbase[k0 + c]; }
    __syncthreads();
#pragma unroll
    for (int c = 0; c < 8; ++c) { xs[srow][scol + c] = xv[c]; wsh[srow][scol + c] = wv[c]; }
    __syncthreads();
#pragma unroll
    for (int k = 0; k < 32; ++k) {   // ascending k: exact BLAS accumulation order
      const float a0 = xs[bsub * 4 + 0][k], a1 = xs[bsub * 4 + 1][k];
      const float a2 = xs[bsub * 4 + 2][k], a3 = xs[bsub * 4 + 3][k];
      const float b0 = wsh[esub * 4 + 0][k], b1 = wsh[esub * 4 + 1][k];
      const float b2 = wsh[esub * 4 + 2][k], b3 = wsh[esub * 4 + 3][k];
      acc[0][0] = fmaf(a0, b0, acc[0][0]); acc[0][1] = fmaf(a0, b1, acc[0][1]);
      acc[0][2] = fmaf(a0, b2, acc[0][2]); acc[0][3] = fmaf(a0, b3, acc[0][3]);
      acc[1][0] = fmaf(a1, b0, acc[1][0]); acc[1][1] = fmaf(a1, b1, acc[1][1]);
      acc[1][2] = fmaf(a1, b2, acc[1][2]); acc[1][3] = fmaf(a1, b3, acc[1][3]);
      acc[2][0] = fmaf(a2, b0, acc[2][0]); acc[2][1] = fmaf(a2, b1, acc[2][1]);
      acc[2][2] = fmaf(a2, b2, acc[2][2]); acc[2][3] = fmaf(a2, b3, acc[2][3]);
      acc[3][0] = fmaf(a3, b0, acc[3][0]); acc[3][1] = fmaf(a3, b1, acc[3][1]);
      acc[3][2] = fmaf(a3, b2, acc[3][2]); acc[3][3] = fmaf(a3, b3, acc[3][3]);
    }
  }

#pragma unroll
  for (int ie = 0; ie < 4; ++ie) {
    const int e = bn * 64 + esub * 4 + ie;
    const float bv = bias[e];
#pragma unroll
    for (int ib = 0; ib < 4; ++ib) {
      const int b = bm * 64 + bsub * 4 + ib;
      xw[(size_t)b * OUT_F + e] = acc[ib][ie] + bv;   // single RNE add, like np
    }
  }
}

// ---------------------------------------------------------------------------
// K2: scan, OpenBLAS sgemv_t fp32 mimicry. Arithmetic bit-identical to the
// passing R9/R10 kernels; schedule changes only:
//  - SINGLE wop buffer (LDS 38016 B -> 4 blocks/CU; R10's dbuf cost a 2-round
//    grid serialization). Commit of row i+1 happens at step-i end, after the
//    dot's in-order LDS reads.
//  - tail samples (j>=1016) live in lane-m0 registers (producer == consumer).
//  - newest sample s_{i-1} folded via register fmaf AFTER the static dot (its
//    LDS slot reads +0.0 during the loop; trailing +0.0 adds are bit-neutral)
//    and written to smp for steps >= i+1. Removes the sigma->write->read
//    step-boundary serialization.
//  - xw[i]/u[i] prefetched one step ahead (hides ~200cyc L2 latency).
// Layout: 8 rows/wave (g=lane>>3), lane m=lane&7 owns partial m (j≡m mod 8,
// ascending, FMA); AVX tree ((P0+P4)+(P2+P6))+((P1+P5)+(P3+P7)); scalar tail
// j=1016..1022; logit = xw_i + dot; sigma in double, RNE to fp32.
// ---------------------------------------------------------------------------
__global__ __launch_bounds__(64, 1) void k_scan32(const float* __restrict__ w,
                                                  const float* __restrict__ u,
                                                  const float* __restrict__ xw,
                                                  float* __restrict__ out_s,
                                                  float* __restrict__ out_l) {
  __shared__ float smp[8][8][SROW];   // 33792 B  samples, permuted
  __shared__ float wop[8][SROW];      //  4224 B  current Wo row (single buffer)
  const int lane = threadIdx.x;
  const int g = lane >> 3;   // row group 0..7
  const int m = lane & 7;    // partial index

  // zero-init LDS (zeros are bit-exact filler terms for the static dot)
  for (int idx = lane; idx < 8 * 8 * SROW; idx += 64) (&smp[0][0][0])[idx] = 0.0f;
  for (int idx = lane; idx < 8 * SROW; idx += 64) (&wop[0][0])[idx] = 0.0f;

  const int r = blockIdx.x * 8 + g;
  const float* xwr = xw + (size_t)r * OUT_F;
  const float* ur = u + (size_t)r * OUT_F;
  float* osr = out_s + (size_t)r * OUT_F;
  float* olr = out_l + (size_t)r * OUT_F;

  // stage row 0 directly into wop; prefetch row 1 into registers
  {
    const float* w0 = w + (size_t)0 * W_K + IN_F;
#pragma unroll
    for (int c = 0; c < 16; ++c) {
      const int jj = lane + 64 * c;
      if (jj < OUT_F - 1) wop[jj & 7][jj >> 3] = w0[jj];
    }
  }
  float pre[16];
  {
    const float* w1 = w + (size_t)1 * W_K + IN_F;
#pragma unroll
    for (int c = 0; c < 16; ++c) {
      const int jj = lane + 64 * c;
      pre[c] = (jj < OUT_F - 1) ? w1[jj] : 0.0f;
    }
  }

  float tail_s[7];
#pragma unroll
  for (int jj = 0; jj < 7; ++jj) tail_s[jj] = 0.0f;

  float s_prev = 0.0f;     // newest sample (valid group-wide after broadcast)
  float xwc = xwr[0];
  float uc = ur[0];

  for (int i = 0; i < OUT_F; ++i) {
    const int iprev = i - 1;
    const bool dofold = (iprev >= 0) && (iprev < 1016);
    const int fm = dofold ? (iprev & 7) : 0;
    const int ft = dofold ? (iprev >> 3) : 0;

    // broadcast reads from current wop row (same addr across lanes -> free)
    float wt[7];
#pragma unroll
    for (int jj = 0; jj < 7; ++jj) wt[jj] = wop[jj][127];  // Wo[i][1016+jj]
    const float wfold = wop[fm][ft];                       // Wo[i][iprev]

    // prefetch next step's xw/u (independent; consumed next iteration)
    const int inx = (i + 1 < OUT_F) ? i + 1 : OUT_F - 1;
    const float xwn = xwr[inx];
    const float un = ur[inx];

    // static full-length dot: ascending t, FMA (unwritten slots = +0.0 exact)
    float P = 0.0f;
    const float* sp = &smp[g][m][0];
    const float* wp = &wop[m][0];
#pragma unroll
    for (int q = 0; q < 32; ++q) {
      const float4 s4 = *(const float4*)(sp + 4 * q);
      const float4 w4 = *(const float4*)(wp + 4 * q);
      P = fmaf(s4.x, w4.x, P);
      P = fmaf(s4.y, w4.y, P);
      P = fmaf(s4.z, w4.z, P);
      P = fmaf(s4.w, w4.w, P);
    }
    // fold newest sample as the last nonzero term of its partial (bit-exact)
    {
      const float mult = (dofold && (m == fm)) ? s_prev : 0.0f;
      P = fmaf(mult, wfold, P);
    }
    // publish s_{i-1} to LDS for steps >= i+1 (after this dot's reads)
    if (dofold && (m == fm)) smp[g][m][ft] = s_prev;

    // AVX horizontal tree: ((P0+P4)+(P2+P6)) + ((P1+P5)+(P3+P7))
    float t1 = P + __shfl_xor(P, 4);
    float t2 = t1 + __shfl_xor(t1, 2);
    float T = t2 + __shfl_xor(t2, 1);

    // lane m==0: scalar tail, logit, sigma, decision, stores
    float s = 0.0f;
    if (m == 0) {
#pragma unroll
      for (int jj = 0; jj < 7; ++jj)
        T = fmaf(tail_s[jj], wt[jj], T);
      const float L = xwc + T;                          // np: xw_i + dot
      const double sd = 1.0 / (1.0 + exp(-(double)L));  // sigma (double, RNE)
      const float sig = (float)sd;
      s = (uc < sig) ? 1.0f : 0.0f;
      osr[i] = s;
      olr[i] = L;
      if (i >= 1016) tail_s[i - 1016] = s;
    }
    // broadcast group decision; becomes s_prev for the next step's fold
    s_prev = __shfl(s, lane & 56);

    // commit prefetched row i+1; prefetch row i+2
    if (i + 1 < OUT_F) {
#pragma unroll
      for (int c = 0; c < 16; ++c) {
        const int jj = lane + 64 * c;
        if (jj < OUT_F - 1) wop[jj & 7][jj >> 3] = pre[c];
      }
      if (i + 2 < OUT_F) {
        const float* wn = w + (size_t)(i + 2) * W_K + IN_F;
#pragma unroll
        for (int c = 0; c < 16; ++c) {
          const int jj = lane + 64 * c;
          pre[c] = (jj < OUT_F - 1) ? wn[jj] : 0.0f;
        }
      }
    }
    xwc = xwn;
    uc = un;
  }
}

// ---------------------------------------------------------------------------
extern "C" void kernel_launch(void* const* d_in, const int* in_sizes, int n_in,
                              void* d_out, int out_size, void* d_ws, size_t ws_size,
                              hipStream_t stream) {
  float* out_s = (float*)d_out;                      // samples (B x OUT_F) fp32
  float* out_l = out_s + (size_t)BATCH * OUT_F;      // logits  (B x OUT_F) fp32
  const int nfill = (BATCH * OUT_F) / (256 * 4);

  const bool shapes_ok =
      n_in == 4 &&
      in_sizes[0] == BATCH * IN_F && in_sizes[1] == OUT_F * W_K &&
      in_sizes[2] == OUT_F && in_sizes[3] == BATCH * OUT_F &&
      out_size == 2 * BATCH * OUT_F;
  if (!shapes_ok) {
    k_fill<<<nfill, 256, 0, stream>>>(out_s, 11.0f);
    return;
  }

  const size_t xw_bytes = (size_t)BATCH * OUT_F * sizeof(float);  // 32 MiB
  if (ws_size < xw_bytes) {
    k_fill<<<nfill, 256, 0, stream>>>(out_s, 7.0f);
    return;
  }

  const float* x = (const float*)d_in[0];     // fp32 (8192 x 512)
  const float* w = (const float*)d_in[1];     // fp32 (1024 x 1535)
  const float* bias = (const float*)d_in[2];  // fp32 (1024)
  const float* u = (const float*)d_in[3];     // fp32 (8192 x 1024)
  float* xw = (float*)d_ws;                   // 32 MiB

  k_gemm32<<<dim3(BATCH / 64, OUT_F / 64), 256, 0, stream>>>(x, w, bias, xw);
  k_scan32<<<BATCH / 8, 64, 0, stream>>>(w, u, xw, out_s, out_l);
}